// Round 9
// baseline (468.992 us; speedup 1.0000x reference)
//
#include <hip/hip_runtime.h>
#include <hip/hip_bf16.h>
#include <cstdint>
#include <cstddef>

#define B_  256
#define Z_  512
#define H_  2048
#define T_  16
#define H3_ 6144

using short8  = __attribute__((ext_vector_type(8))) short;
using bf16x8  = __attribute__((ext_vector_type(8))) __bf16;
using f32x4   = __attribute__((ext_vector_type(4))) float;
using f32x16  = __attribute__((ext_vector_type(16))) float;

__device__ __forceinline__ f32x4 mfma_bf16(short8 a, short8 b, f32x4 c) {
  return __builtin_amdgcn_mfma_f32_16x16x32_bf16(
      __builtin_bit_cast(bf16x8, a), __builtin_bit_cast(bf16x8, b), c, 0, 0, 0);
}
__device__ __forceinline__ f32x16 mfma_bf16_32(short8 a, short8 b, f32x16 c) {
  return __builtin_amdgcn_mfma_f32_32x32x16_bf16(
      __builtin_bit_cast(bf16x8, a), __builtin_bit_cast(bf16x8, b), c, 0, 0, 0);
}

__device__ __forceinline__ unsigned short f2bf(float f) {
  unsigned int u = __builtin_bit_cast(unsigned int, f);
  u = (u + 0x7FFFu + ((u >> 16) & 1u)) >> 16;
  return (unsigned short)u;
}

__device__ __forceinline__ float sigmoidf_(float x) { return 1.0f / (1.0f + __expf(-x)); }

// LDS XOR swizzle: tiles are [rows][64] bf16 (128 B rows = 8x16B chunks).
__device__ __forceinline__ int swz(int row, int chunk) {
  return row * 64 + ((chunk ^ (row & 7)) << 3);   // ushort element offset
}

// Packed B-fragment layout for mfma_32x32x16 wf loads:
// block = (grp=row>>5)*(K/16) + (s=col>>4), 512 els/block;
// within block: lane = ((col>>3)&1)*32 + (row&31), el j = col&7.
__device__ __forceinline__ size_t pidx(int row, int col, int K) {
  const int grp = row >> 5, prow = row & 31;
  const int s = col >> 4, lh = (col >> 3) & 1, j = col & 7;
  return (((size_t)grp * (K >> 4) + s) << 9) + (((lh << 5) | prow) << 3) + j;
}

// ---------------------------------------------------------------------------
// GRU step v6: W from packed global (no LDS for W), A staged in LDS dbuf.
// Tile M=64 x 128 gate-cols. Grid 256, 512 thr, 8 waves = (gate 4) x (kk 2);
// per wave per 64-K chunk: 2 packed-wf global loads + 4 af LDS reads +
// 4 mfma_32x32x16 (2 k-slices x 2 m-halves). 1 barrier/chunk (A dbuf).
// kk halves cross-wave-reduced once per step; fused gate epilogue.
// XCD swizzle: xcd = colgrp % 8; a colgroup's 4 m-sharers are co-XCD.
// ---------------------------------------------------------------------------
__global__ __launch_bounds__(512, 1) void gru_step6(
    const unsigned short* __restrict__ A, int K,
    const unsigned short* __restrict__ Wr,
    const unsigned short* __restrict__ Wz,
    const unsigned short* __restrict__ Wn,
    const unsigned short* __restrict__ Whn,
    const float* __restrict__ cr, const float* __restrict__ cz,
    const float* __restrict__ cn, const float* __restrict__ chn,
    float hn_scale,
    const float* __restrict__ h_old,
    float* __restrict__ h_new,
    unsigned short* __restrict__ h_hist)
{
  __shared__ __align__(16) unsigned short sA[2][4096];   // 16 KB A dbuf
  __shared__ float rawred[8][16][64];                     // 32 KB kk-reduce
  __shared__ float LDSf[4][64][33];                       // 33.8 KB exchange
  const int bid = blockIdx.x, tid = threadIdx.x;
  const int xcd = bid & 7, rst = bid >> 3;
  const int m_idx = rst & 3, gg = rst >> 2;
  const int grp = gg * 8 + xcd;            // [0,64) h-col group
  const int m0 = m_idx * 64;
  const int gh0 = grp * 32;                // h-col base
  const int wave = tid >> 6, lane = tid & 63;
  const int gate = wave & 3, kk = wave >> 2;
  const int lh = lane >> 5, l31 = lane & 31;

  const unsigned short* Wg =
      (gate == 0) ? Wr : (gate == 1) ? Wz : (gate == 2) ? Wn : Whn;
  const int ns = K >> 4;                   // total k-slices
  // this wave's packed-wf base (slice s block + lane offset)
  const unsigned short* wbase = Wg + (((size_t)grp * ns) << 9) + lane * 8;

  // A staging: thread -> (row = tid>>3, chunk = tid&7), 1 dwordx4 each
  const int arow = tid >> 3, achk = tid & 7;
  const size_t aoff = (size_t)(m0 + arow) * K + achk * 8;
  const int sa_d = swz(arow, achk);

  f32x16 acc0 = {}, acc1 = {};             // m-half 0 / 1
  uint4 Ar, W0, W1, Wn0, Wn1;

  const int nIter = K >> 6;
  Ar = *(const uint4*)(A + aoff);
  {
    const size_t sb = ((size_t)(kk * 2)) << 9;
    W0 = *(const uint4*)(wbase + sb);
    W1 = *(const uint4*)(wbase + sb + 512);
  }
  for (int it = 0; it < nIter; ++it) {
    const int b = it & 1;
    *(uint4*)(sA[b] + sa_d) = Ar;
    __syncthreads();
    if (it + 1 < nIter) {
      Ar = *(const uint4*)(A + aoff + ((it + 1) << 6));
      const size_t sb = ((size_t)((it + 1) * 4 + kk * 2)) << 9;
      Wn0 = *(const uint4*)(wbase + sb);
      Wn1 = *(const uint4*)(wbase + sb + 512);
    }
#pragma unroll
    for (int ksi = 0; ksi < 2; ++ksi) {
      const int ch = (kk * 2 + ksi) * 2 + lh;
      short8 af0 = *(const short8*)(sA[b] + swz(l31, ch));
      short8 af1 = *(const short8*)(sA[b] + swz(32 + l31, ch));
      short8 wf = __builtin_bit_cast(short8, ksi ? W1 : W0);
      acc0 = mfma_bf16_32(af0, wf, acc0);
      acc1 = mfma_bf16_32(af1, wf, acc1);
    }
    W0 = Wn0; W1 = Wn1;
  }

  // ---- cross-wave kk reduction ----
  __syncthreads();
  if (kk == 1) {
#pragma unroll
    for (int r = 0; r < 16; ++r) rawred[gate * 2    ][r][lane] = acc0[r];
#pragma unroll
    for (int r = 0; r < 16; ++r) rawred[gate * 2 + 1][r][lane] = acc1[r];
  }
  __syncthreads();
  if (kk == 0) {
#pragma unroll
    for (int r = 0; r < 16; ++r) acc0[r] += rawred[gate * 2    ][r][lane];
#pragma unroll
    for (int r = 0; r < 16; ++r) acc1[r] += rawred[gate * 2 + 1][r][lane];
    // gate exchange: C layout col=lane&31, row=(reg&3)+8*(reg>>2)+4*(lane>>5)
#pragma unroll
    for (int r = 0; r < 16; ++r) {
      const int trow = (r & 3) + 8 * (r >> 2) + 4 * lh;
      LDSf[gate][trow     ][l31] = acc0[r];
      LDSf[gate][32 + trow][l31] = acc1[r];
    }
  }
  __syncthreads();
  {
    const int row = tid >> 3, c0 = (tid & 7) * 4;
    const int grow = m0 + row;
#pragma unroll
    for (int j = 0; j < 4; ++j) {
      const int col = c0 + j;
      const int gcol = gh0 + col;
      const float R   = sigmoidf_(LDSf[0][row][col] + cr[gcol]);
      const float U   = sigmoidf_(LDSf[1][row][col] + cz[gcol]);
      const float HNv = hn_scale * LDSf[3][row][col] + chn[gcol];
      const float Nv  = tanhf(LDSf[2][row][col] + cn[gcol] + R * HNv);
      const float ho  = h_old ? h_old[(size_t)grow * H_ + gcol] : 0.0f;
      const float hv  = (1.0f - U) * Nv + U * ho;
      h_new[(size_t)grow * H_ + gcol]  = hv;
      h_hist[(size_t)grow * H_ + gcol] = f2bf(hv);
    }
  }
}

// ---------------------------------------------------------------------------
// Generic bf16 GEMM, C = A @ B^T (+add)(+bias)(*scale). WG tile 32x64.
// Grid = (M/32, N/64). Used only for the small x0 GEMM (M=256).
// ---------------------------------------------------------------------------
__global__ __launch_bounds__(256) void gemm_bt(
    const unsigned short* __restrict__ A,
    const unsigned short* __restrict__ Bw,
    int K,
    const float* __restrict__ addsrc, int add_ld,
    const float* __restrict__ bias,
    const float* __restrict__ scale_ptr,
    unsigned short* __restrict__ out_bf,
    float* __restrict__ out_f, int ldo)
{
  __shared__ unsigned short sA[32 * 64];
  __shared__ unsigned short sB[64 * 64];
  const int tid  = threadIdx.x;
  const int m0   = blockIdx.x * 32, n0 = blockIdx.y * 64;
  const int wave = tid >> 6, lane = tid & 63;
  const int wr = wave & 1, wc = wave >> 1;
  const int q = lane >> 4, c16 = lane & 15;
  const int lr = tid >> 3, lc8 = tid & 7;
  f32x4 acc0 = {}, acc1 = {};
  const size_t rowA  = (size_t)(m0 + lr) * K;
  const size_t rowB0 = (size_t)(n0 + lr) * K;
  const size_t rowB1 = (size_t)(n0 + 32 + lr) * K;
  for (int k0 = 0; k0 < K; k0 += 64) {
    const int gc = k0 + lc8 * 8;
    uint4 ra  = *(const uint4*)(A  + rowA  + gc);
    uint4 rb0 = *(const uint4*)(Bw + rowB0 + gc);
    uint4 rb1 = *(const uint4*)(Bw + rowB1 + gc);
    __syncthreads();
    *(uint4*)(sA + swz(lr, lc8))      = ra;
    *(uint4*)(sB + swz(lr, lc8))      = rb0;
    *(uint4*)(sB + swz(32 + lr, lc8)) = rb1;
    __syncthreads();
#pragma unroll
    for (int kk = 0; kk < 2; ++kk) {
      const int arow = wr * 16 + c16;
      short8 af = *(const short8*)(sA + swz(arow, kk * 4 + q));
      const int brow = wc * 32 + c16;
      short8 b0 = *(const short8*)(sB + swz(brow, kk * 4 + q));
      acc0 = mfma_bf16(af, b0, acc0);
      short8 b1 = *(const short8*)(sB + swz(brow + 16, kk * 4 + q));
      acc1 = mfma_bf16(af, b1, acc1);
    }
  }
  const float scale = scale_ptr ? *scale_ptr : 1.0f;
#pragma unroll
  for (int cf = 0; cf < 2; ++cf) {
    f32x4 a = cf ? acc1 : acc0;
#pragma unroll
    for (int v = 0; v < 4; ++v) {
      const int row = m0 + wr * 16 + q * 4 + v;
      const int col = n0 + wc * 32 + cf * 16 + c16;
      float val = a[v] * scale;
      if (addsrc) val += addsrc[(size_t)row * add_ld + col];
      if (bias)   val += bias[col];
      if (out_f)  out_f[(size_t)row * ldo + col] = val;
      if (out_bf) out_bf[(size_t)row * ldo + col] = f2bf(val);
    }
  }
}

// ---------------------------------------------------------------------------
// 64x64-tile bf16 GEMM core, C = A @ B^T (+add)(+bias). 4 waves of 32x32.
// pack_K > 0: write out_bf in packed B-fragment layout (pidx) with that K.
// ---------------------------------------------------------------------------
__device__ __forceinline__ void dev_gemm64core(
    unsigned short* sA, unsigned short* sB,
    const unsigned short* __restrict__ A,
    const unsigned short* __restrict__ Bw,
    int K,
    const float* __restrict__ addsrc, int add_ld,
    const float* __restrict__ bias,
    unsigned short* __restrict__ out_bf,
    float* __restrict__ out_f, int ldo, int mi, int ni, int pack_K)
{
  const int tid  = threadIdx.x;
  const int m0   = mi * 64, n0 = ni * 64;
  const int wave = tid >> 6, lane = tid & 63;
  const int wr = wave & 1, wc = wave >> 1;
  const int q = lane >> 4, c16 = lane & 15;
  const int lr = tid >> 3, lc8 = tid & 7;
  f32x4 acc[2][2] = {};
  const size_t aoff = (size_t)(m0 + lr) * K;
  const size_t boff = (size_t)(n0 + lr) * K;
  const size_t s32  = (size_t)32 * K;

  uint4 ra0, ra1, rb0, rb1;
  auto LOAD = [&](int k0) {
    const int gc = k0 + lc8 * 8;
    ra0 = *(const uint4*)(A  + aoff + gc);
    ra1 = *(const uint4*)(A  + aoff + s32 + gc);
    rb0 = *(const uint4*)(Bw + boff + gc);
    rb1 = *(const uint4*)(Bw + boff + s32 + gc);
  };

  const int nIter = K >> 6;
  LOAD(0);
  for (int it = 0; it < nIter; ++it) {
    __syncthreads();
    *(uint4*)(sA + swz(lr, lc8))      = ra0;
    *(uint4*)(sA + swz(lr + 32, lc8)) = ra1;
    *(uint4*)(sB + swz(lr, lc8))      = rb0;
    *(uint4*)(sB + swz(lr + 32, lc8)) = rb1;
    __syncthreads();
    if (it + 1 < nIter) LOAD((it + 1) << 6);
#pragma unroll
    for (int kk = 0; kk < 2; ++kk) {
      short8 af0 = *(const short8*)(sA + swz(wr * 32 + c16,      kk * 4 + q));
      short8 af1 = *(const short8*)(sA + swz(wr * 32 + 16 + c16, kk * 4 + q));
      short8 bf0 = *(const short8*)(sB + swz(wc * 32 + c16,      kk * 4 + q));
      short8 bf1 = *(const short8*)(sB + swz(wc * 32 + 16 + c16, kk * 4 + q));
      acc[0][0] = mfma_bf16(af0, bf0, acc[0][0]);
      acc[0][1] = mfma_bf16(af0, bf1, acc[0][1]);
      acc[1][0] = mfma_bf16(af1, bf0, acc[1][0]);
      acc[1][1] = mfma_bf16(af1, bf1, acc[1][1]);
    }
  }
#pragma unroll
  for (int i = 0; i < 2; ++i) {
#pragma unroll
    for (int j = 0; j < 2; ++j) {
#pragma unroll
      for (int v = 0; v < 4; ++v) {
        const int row = m0 + wr * 32 + i * 16 + q * 4 + v;
        const int col = n0 + wc * 32 + j * 16 + c16;
        float val = acc[i][j][v];
        if (addsrc) val += addsrc[(size_t)row * add_ld + col];
        if (bias)   val += bias[col];
        if (out_f)  out_f[(size_t)row * ldo + col] = val;
        if (out_bf) {
          if (pack_K) out_bf[pidx(row, col, pack_K)] = f2bf(val);
          else        out_bf[(size_t)row * ldo + col] = f2bf(val);
        }
      }
    }
  }
}

__global__ __launch_bounds__(256) void gemm_bt64(
    const unsigned short* __restrict__ A,
    const unsigned short* __restrict__ Bw,
    int K,
    const float* __restrict__ addsrc, int add_ld,
    const float* __restrict__ bias,
    unsigned short* __restrict__ out_bf,
    float* __restrict__ out_f, int ldo)
{
  __shared__ unsigned short sA[64 * 64];
  __shared__ unsigned short sB[64 * 64];
  dev_gemm64core(sA, sB, A, Bw, K, addsrc, add_ld, bias, out_bf, out_f, ldo,
                 blockIdx.x, blockIdx.y, 0);
}

// all 3 W_comb GEMMs in one launch, packed output. Grid (32, 96).
__global__ __launch_bounds__(256) void gemm_wsum(
    const unsigned short* __restrict__ w_ih_q,
    const unsigned short* __restrict__ lin_wT_q,
    const float* __restrict__ w_hh,
    unsigned short* __restrict__ Wsum_r_p,
    unsigned short* __restrict__ Wsum_z_p,
    unsigned short* __restrict__ Wsum_n_p)
{
  __shared__ unsigned short sA[64 * 64];
  __shared__ unsigned short sB[64 * 64];
  const int g = blockIdx.y >> 5, ni = blockIdx.y & 31;
  const float* adds = (g < 2) ? (w_hh + (size_t)g * H_ * H_) : nullptr;
  unsigned short* outw = (g == 0) ? Wsum_r_p : (g == 1) ? Wsum_z_p : Wsum_n_p;
  dev_gemm64core(sA, sB, w_ih_q + (size_t)g * H_ * Z_, lin_wT_q, Z_,
                 adds, H_, nullptr, outw, nullptr, H_, blockIdx.x, ni, H_);
}

// ---------------------------------------------------------------------------
// merged quantization; w_ih -> row-major AND packed(K=512); w_hh_n -> packed.
// ---------------------------------------------------------------------------
__global__ __launch_bounds__(256) void quant_all(
    const float* __restrict__ z, const float* __restrict__ fc_w,
    const float* __restrict__ w_ih, const float* __restrict__ w_hh,
    const float* __restrict__ lin_w,
    unsigned short* __restrict__ z_q, unsigned short* __restrict__ fc_w_q,
    unsigned short* __restrict__ w_ih_q, unsigned short* __restrict__ w_ih_p,
    unsigned short* __restrict__ w_hhn_p, unsigned short* __restrict__ lin_w_q)
{
  const int i = blockIdx.x * 256 + threadIdx.x;
  if (i >= 2195456) return;
  if (i < 32768) {
    float4 v = ((const float4*)z)[i];
    ushort4 o; o.x = f2bf(v.x); o.y = f2bf(v.y); o.z = f2bf(v.z); o.w = f2bf(v.w);
    ((ushort4*)z_q)[i] = o;
  } else if (i < 98304) {
    const int idx = i - 32768;
    float4 v = ((const float4*)fc_w)[idx];
    ushort4 o; o.x = f2bf(v.x); o.y = f2bf(v.y); o.z = f2bf(v.z); o.w = f2bf(v.w);
    ((ushort4*)fc_w_q)[idx] = o;
  } else if (i < 884736) {
    const int idx = i - 98304;                  // float4 within [6144][512]
    float4 v = ((const float4*)w_ih)[idx];
    ushort4 o; o.x = f2bf(v.x); o.y = f2bf(v.y); o.z = f2bf(v.z); o.w = f2bf(v.w);
    ((ushort4*)w_ih_q)[idx] = o;                // row-major (gemm_wsum A-op)
    const int row = idx >> 7, k0 = (idx & 127) << 2;
    const int gate = row >> 11, r2 = row & 2047;
    *(ushort4*)(w_ih_p + (size_t)gate * 1048576 + pidx(r2, k0, Z_)) = o;
  } else if (i < 1933312) {
    const int idx = i - 884736;                 // float4 within [2048][2048]
    float4 v = ((const float4*)(w_hh + (size_t)2 * H_ * H_))[idx];
    ushort4 o; o.x = f2bf(v.x); o.y = f2bf(v.y); o.z = f2bf(v.z); o.w = f2bf(v.w);
    const int row = idx >> 9, k0 = (idx & 511) << 2;
    *(ushort4*)(w_hhn_p + pidx(row, k0, H_)) = o;
  } else {
    const int idx = i - 1933312;
    float4 v = ((const float4*)lin_w)[idx];
    ushort4 o; o.x = f2bf(v.x); o.y = f2bf(v.y); o.z = f2bf(v.z); o.w = f2bf(v.w);
    ((ushort4*)lin_w_q)[idx] = o;
  }
}

// lin_w [512][2048] f32 -> lin_wT [2048][512] bf16
__global__ __launch_bounds__(256) void transq(const float* __restrict__ s,
                                              unsigned short* __restrict__ d) {
  __shared__ float tile[32][33];
  const int tx = threadIdx.x & 31, ty = threadIdx.x >> 5;
  const int k0 = blockIdx.x * 32, z0 = blockIdx.y * 32;
#pragma unroll
  for (int j = 0; j < 4; ++j)
    tile[ty + j * 8][tx] = s[(size_t)(z0 + ty + j * 8) * H_ + k0 + tx];
  __syncthreads();
#pragma unroll
  for (int j = 0; j < 4; ++j)
    d[(size_t)(k0 + ty + j * 8) * Z_ + z0 + tx] = f2bf(tile[tx][ty + j * 8]);
}

// t1 = W^T u.  grid 8, block 256 (4 waves x 128 rows each).
__global__ void sigma1(const float* __restrict__ W, const float* __restrict__ u,
                       float* __restrict__ t1) {
  __shared__ float part[4][64];
  const int lane = threadIdx.x & 63, wv = threadIdx.x >> 6;
  const int col = blockIdx.x * 64 + lane;
  float s = 0.f;
  for (int r = wv * 128; r < wv * 128 + 128; ++r)
    s += W[(size_t)r * Z_ + col] * u[r];
  part[wv][lane] = s;
  __syncthreads();
  if (wv == 0)
    t1[col] = part[0][lane] + part[1][lane] + part[2][lane] + part[3][lane];
}

// t2 = W @ normalize(t1); per-WG redundant norm recompute (t1 is 2KB, L2-hot).
__global__ void sigma2(const float* __restrict__ W, const float* __restrict__ t1,
                       float* __restrict__ t2) {
  __shared__ float red[256];
  const int tid = threadIdx.x;
  float p = 0.f;
  for (int c = tid; c < Z_; c += 256) { float v = t1[c]; p += v * v; }
  red[tid] = p;
  __syncthreads();
  for (int s = 128; s > 0; s >>= 1) {
    if (tid < s) red[tid] += red[tid + s];
    __syncthreads();
  }
  const float invn = 1.0f / (sqrtf(red[0]) + 1e-12f);
  const int lane = tid & 63, wv = tid >> 6;
  const int row = blockIdx.x * 4 + wv;
  float s = 0.f;
  for (int c = lane; c < Z_; c += 64) s += W[(size_t)row * Z_ + c] * t1[c];
#pragma unroll
  for (int off = 32; off > 0; off >>= 1) s += __shfl_down(s, off);
  if (lane == 0) t2[row] = s * invn;
}

__global__ void sigma3(const float* __restrict__ t2, float* __restrict__ inv_sig) {
  __shared__ float red[256];
  int t = threadIdx.x;
  float v0 = t2[t], v1 = t2[t + 256];
  red[t] = v0 * v0 + v1 * v1;
  __syncthreads();
  for (int s = 128; s > 0; s >>= 1) {
    if (t < s) red[t] += red[t + s];
    __syncthreads();
  }
  if (t == 0) {
    float s2  = red[0];
    float sig = s2 / (sqrtf(s2) + 1e-12f);
    inv_sig[0] = 1.0f / sig;
  }
}

// dvec[row] = dot(w_ih[row], lin_b) fused with the gate-constant writes.
__global__ __launch_bounds__(256) void dots2_k(
    const float* __restrict__ w, const float* __restrict__ lb,
    const float* __restrict__ b_ih, const float* __restrict__ b_hh,
    float* __restrict__ c0r, float* __restrict__ c0z, float* __restrict__ c0n,
    float* __restrict__ c1r, float* __restrict__ c1z, float* __restrict__ c1n,
    float* __restrict__ chn)
{
  const int wave = threadIdx.x >> 6, lane = threadIdx.x & 63;
#pragma unroll
  for (int i = 0; i < 4; ++i) {
    int row = blockIdx.x * 16 + wave * 4 + i;
    float s = 0.f;
    for (int c = lane; c < Z_; c += 64) s += w[(size_t)row * Z_ + c] * lb[c];
#pragma unroll
    for (int off = 32; off > 0; off >>= 1) s += __shfl_down(s, off);
    if (lane == 0) {
      const int g = row >> 11, j = row & 2047;
      const float bi = b_ih[row], bh = b_hh[row];
      if (g == 0)      { c0r[j] = bi + bh; c1r[j] = bi + bh + s; }
      else if (g == 1) { c0z[j] = bi + bh; c1z[j] = bi + bh + s; }
      else             { c0n[j] = bi;      c1n[j] = bi + s;      chn[j] = bh; }
    }
  }
}

// BN over batch per (t,z) + transpose [T,B,Z] -> [B,T,Z]. Grid (16, 8).
__global__ __launch_bounds__(256) void bn_k(const float* __restrict__ outs,
                                            float* __restrict__ y) {
  __shared__ float s_sum[4][64], s_sq[4][64], s_mean[64], s_inv[64];
  const int t = blockIdx.x, zb = blockIdx.y;
  const int zl = threadIdx.x & 63, bp = threadIdx.x >> 6;
  const int z = zb * 64 + zl;
  float sum = 0.f, sq = 0.f;
  for (int b = bp * 64; b < bp * 64 + 64; ++b) {
    float v = outs[(size_t)(t * 256 + b) * Z_ + z];
    sum += v; sq += v * v;
  }
  s_sum[bp][zl] = sum; s_sq[bp][zl] = sq;
  __syncthreads();
  if (bp == 0) {
    float S = s_sum[0][zl] + s_sum[1][zl] + s_sum[2][zl] + s_sum[3][zl];
    float Q = s_sq[0][zl] + s_sq[1][zl] + s_sq[2][zl] + s_sq[3][zl];
    float mean = S * (1.0f / 256.0f);
    float var  = Q * (1.0f / 256.0f) - mean * mean;
    s_mean[zl] = mean;
    s_inv[zl]  = rsqrtf(var + 1e-5f);
  }
  __syncthreads();
  const float mean = s_mean[zl], inv = s_inv[zl];
  for (int b = bp * 64; b < bp * 64 + 64; ++b) {
    float v = outs[(size_t)(t * 256 + b) * Z_ + z];
    y[(size_t)(b * T_ + t) * Z_ + z] = (v - mean) * inv;
  }
}

// ---------------------------------------------------------------------------
extern "C" void kernel_launch(void* const* d_in, const int* in_sizes, int n_in,
                              void* d_out, int out_size, void* d_ws, size_t ws_size,
                              hipStream_t stream) {
  const float* z     = (const float*)d_in[0];
  const float* fc_w  = (const float*)d_in[1];
  const float* fc_b  = (const float*)d_in[2];
  const float* fc_u  = (const float*)d_in[3];
  const float* w_ih  = (const float*)d_in[4];
  const float* w_hh  = (const float*)d_in[5];
  const float* b_ih  = (const float*)d_in[6];
  const float* b_hh  = (const float*)d_in[7];
  const float* lin_w = (const float*)d_in[8];
  const float* lin_b = (const float*)d_in[9];
  float* out = (float*)d_out;

  char* ws = (char*)d_ws;
  size_t off = 0;
  auto alloc = [&](size_t bytes) -> void* {
    off = (off + 255) & ~(size_t)255;
    void* p = ws + off;
    off += bytes;
    return p;
  };
  unsigned short* w_ih_q   = (unsigned short*)alloc((size_t)H3_ * Z_ * 2);
  unsigned short* w_ih_p   = (unsigned short*)alloc((size_t)H3_ * Z_ * 2);
  unsigned short* w_hhn_p  = (unsigned short*)alloc((size_t)H_ * H_ * 2);
  unsigned short* lin_w_q  = (unsigned short*)alloc((size_t)Z_ * H_ * 2);
  unsigned short* lin_wT_q = (unsigned short*)alloc((size_t)Z_ * H_ * 2);
  unsigned short* fc_w_q   = (unsigned short*)alloc((size_t)Z_ * Z_ * 2);
  unsigned short* z_q      = (unsigned short*)alloc((size_t)B_ * Z_ * 2);
  unsigned short* x0_q     = (unsigned short*)alloc((size_t)B_ * Z_ * 2);
  unsigned short* Wsum_r_p = (unsigned short*)alloc((size_t)H_ * H_ * 2);
  unsigned short* Wsum_z_p = (unsigned short*)alloc((size_t)H_ * H_ * 2);
  unsigned short* Wsum_n_p = (unsigned short*)alloc((size_t)H_ * H_ * 2);
  unsigned short* Hhist    = (unsigned short*)alloc((size_t)T_ * B_ * H_ * 2);
  float* h_f32 = (float*)alloc((size_t)2 * B_ * H_ * 4);
  float* outs  = (float*)alloc((size_t)T_ * B_ * Z_ * 4);
  float* c0r = (float*)alloc(H_ * 4);
  float* c0z = (float*)alloc(H_ * 4);
  float* c0n = (float*)alloc(H_ * 4);
  float* c1r = (float*)alloc(H_ * 4);
  float* c1z = (float*)alloc(H_ * 4);
  float* c1n = (float*)alloc(H_ * 4);
  float* chn = (float*)alloc(H_ * 4);
  float* t1v = (float*)alloc(Z_ * 4);
  float* t2v = (float*)alloc(Z_ * 4);
  float* invsig = (float*)alloc(256);
  (void)in_sizes; (void)n_in; (void)out_size; (void)ws_size;

  quant_all<<<dim3(2195456 / 256), 256, 0, stream>>>(
      z, fc_w, w_ih, w_hh, lin_w, z_q, fc_w_q, w_ih_q, w_ih_p, w_hhn_p, lin_w_q);
  transq<<<dim3(64, 16), 256, 0, stream>>>(lin_w, lin_wT_q);
  sigma1<<<8, 256, 0, stream>>>(fc_w, fc_u, t1v);
  sigma2<<<128, 256, 0, stream>>>(fc_w, t1v, t2v);
  sigma3<<<1, 256, 0, stream>>>(t2v, invsig);
  dots2_k<<<384, 256, 0, stream>>>(w_ih, lin_b, b_ih, b_hh,
                                   c0r, c0z, c0n, c1r, c1z, c1n, chn);

  // x0 = (z @ fc_w^T) * inv_sigma + fc_b   -> bf16 (row-major)
  gemm_bt<<<dim3(B_ / 32, Z_ / 64), 256, 0, stream>>>(
      z_q, fc_w_q, Z_, nullptr, 0, fc_b, invsig, x0_q, nullptr, Z_);

  // W_comb_g = w_ih_g @ lin_w (+ w_hh_g for r,z) -> packed bf16, 1 launch
  gemm_wsum<<<dim3(H_ / 64, 96), 256, 0, stream>>>(
      w_ih_q, lin_wT_q, w_hh, Wsum_r_p, Wsum_z_p, Wsum_n_p);

  for (int t = 0; t < T_; ++t) {
    if (t == 0) {
      gru_step6<<<256, 512, 0, stream>>>(
          x0_q, Z_,
          w_ih_p, w_ih_p + 1048576, w_ih_p + 2 * 1048576,
          w_ih_p /* dummy, scaled by 0 */,
          c0r, c0z, c0n, chn, 0.0f, nullptr, h_f32, Hhist);
    } else {
      gru_step6<<<256, 512, 0, stream>>>(
          Hhist + (size_t)(t - 1) * B_ * H_, H_,
          Wsum_r_p, Wsum_z_p, Wsum_n_p, w_hhn_p,
          c1r, c1z, c1n, chn, 1.0f,
          h_f32 + (size_t)((t - 1) & 1) * B_ * H_,
          h_f32 + (size_t)(t & 1) * B_ * H_,
          Hhist + (size_t)t * B_ * H_);
    }
  }

  // outs[t*256+b][z] = Hhist[t][b] @ lin_w^T + lin_b   (f32)
  gemm_bt64<<<dim3(T_ * B_ / 64, Z_ / 64), 256, 0, stream>>>(
      Hhist, lin_w_q, H_, nullptr, 0, lin_b, nullptr, outs, Z_);

  bn_k<<<dim3(T_, Z_ / 64), 256, 0, stream>>>(outs, out);
}

// Round 10
// 411.389 us; speedup vs baseline: 1.1400x; 1.1400x over previous
//
#include <hip/hip_runtime.h>
#include <hip/hip_bf16.h>
#include <cstdint>
#include <cstddef>

#define B_  256
#define Z_  512
#define H_  2048
#define T_  16
#define H3_ 6144

using short8  = __attribute__((ext_vector_type(8))) short;
using bf16x8  = __attribute__((ext_vector_type(8))) __bf16;
using f32x4   = __attribute__((ext_vector_type(4))) float;
using f32x16  = __attribute__((ext_vector_type(16))) float;

__device__ __forceinline__ f32x4 mfma_bf16(short8 a, short8 b, f32x4 c) {
  return __builtin_amdgcn_mfma_f32_16x16x32_bf16(
      __builtin_bit_cast(bf16x8, a), __builtin_bit_cast(bf16x8, b), c, 0, 0, 0);
}
__device__ __forceinline__ f32x16 mfma_bf16_32(short8 a, short8 b, f32x16 c) {
  return __builtin_amdgcn_mfma_f32_32x32x16_bf16(
      __builtin_bit_cast(bf16x8, a), __builtin_bit_cast(bf16x8, b), c, 0, 0, 0);
}

__device__ __forceinline__ unsigned short f2bf(float f) {
  unsigned int u = __builtin_bit_cast(unsigned int, f);
  u = (u + 0x7FFFu + ((u >> 16) & 1u)) >> 16;
  return (unsigned short)u;
}

__device__ __forceinline__ float sigmoidf_(float x) { return 1.0f / (1.0f + __expf(-x)); }

// LDS XOR swizzle: tiles are [rows][64] bf16 (128 B rows = 8x16B chunks).
__device__ __forceinline__ int swz(int row, int chunk) {
  return row * 64 + ((chunk ^ (row & 7)) << 3);   // ushort element offset
}

// ---------------------------------------------------------------------------
// GRU step v7 = v4 skeleton + (2 mh x 2 gates x 1 slice) register tiling.
// Tile M=64 x 128 gate-cols. Grid 256, 512 thr, 8 waves = (slice 4) x
// (gate-pair 2). Per wave per 64-K chunk: 2 af + 2 wf LDS reads, 4 mfma
// (1.0 reads/mfma vs v4's 2.0; LDS 88KB -> 56KB per chunk). Cross-slice
// 4-way reduce once per step via dedicated LDS region; fused epilogue.
// XCD swizzle: xcd = colgrp % 8; a colgroup's 4 m-sharers are co-XCD.
// ---------------------------------------------------------------------------
__global__ __launch_bounds__(512, 1) void gru_step7(
    const unsigned short* __restrict__ A, int K,
    const unsigned short* __restrict__ Wr,
    const unsigned short* __restrict__ Wz,
    const unsigned short* __restrict__ Wn,
    const unsigned short* __restrict__ Whn,
    const float* __restrict__ cr, const float* __restrict__ cz,
    const float* __restrict__ cn, const float* __restrict__ chn,
    float hn_scale,
    const float* __restrict__ h_old,
    float* __restrict__ h_new,
    unsigned short* __restrict__ h_hist)
{
  // A region: 64x64 ush (8KB) at [0,4096); W region: 128x64 (16KB) at [4096,12288)
  __shared__ __align__(16) unsigned short sbuf[2][12288];   // 48 KB dbuf
  __shared__ float red[6][4096];                             // 96 KB reduce
  float* LDSf = (float*)sbuf;   // [4][64][33] overlay (sbuf dead after loop)
  const int bid = blockIdx.x, tid = threadIdx.x;
  const int xcd = bid & 7, rst = bid >> 3;
  const int m_idx = rst & 3, gg = rst >> 2;
  const int grp = gg * 8 + xcd;            // [0,64) h-col group
  const int m0 = m_idx * 64;
  const int gh0 = grp * 32;                // h-col base
  const int wave = tid >> 6, lane = tid & 63;
  const int s4 = wave & 3, gp = wave >> 2;
  const int lh = lane >> 5, l31 = lane & 31;

  // staging maps (identical to v4): A: 1 dwordx4/thread (64 rows x 8 chunks);
  //                                 W: 2 consecutive dwordx4/thread (128 x 8).
  const int arow = tid >> 3, achk = tid & 7;
  const int wrow = tid >> 2, wc0 = (tid & 3) * 2;
  const unsigned short* wsrc =
      (wrow < 32) ? Wr : (wrow < 64) ? Wz : (wrow < 96) ? Wn : Whn; // wave-uniform
  const size_t aoff = (size_t)(m0 + arow) * K + achk * 8;
  const size_t woff = (size_t)(gh0 + (wrow & 31)) * K + wc0 * 8;
  const int sa_d  = swz(arow, achk);
  const int sw_d0 = 4096 + swz(wrow, wc0 + 0);
  const int sw_d1 = 4096 + swz(wrow, wc0 + 1);

  uint4 Aa, Aw0, Aw1;   // prefetch set A (even chunks)
  uint4 Ba, Bw0, Bw1;   // prefetch set B (odd chunks)

#define LDSET(a, w0, w1, k0)                               \
  {                                                        \
    const int kk_ = (k0);                                  \
    a  = *(const uint4*)(A    + aoff + kk_);               \
    w0 = *(const uint4*)(wsrc + woff + kk_);               \
    w1 = *(const uint4*)(wsrc + woff + kk_ + 8);           \
  }
#define STAGE(s, a, w0, w1)                                \
  {                                                        \
    unsigned short* b_ = sbuf[s];                          \
    *(uint4*)(b_ + sa_d)  = a;                             \
    *(uint4*)(b_ + sw_d0) = w0;                            \
    *(uint4*)(b_ + sw_d1) = w1;                            \
  }

  f32x16 a00 = {}, a01 = {}, a10 = {}, a11 = {};  // [mh][gate-of-pair]
  const int g0r = gp * 64, g1r = gp * 64 + 32;    // gate rows in W region

#define COMP(sb)                                                           \
  {                                                                        \
    const unsigned short* b_ = sbuf[sb];                                   \
    const int ch = s4 * 2 + lh;                                            \
    short8 af0 = *(const short8*)(b_ + swz(l31, ch));                      \
    short8 af1 = *(const short8*)(b_ + swz(32 + l31, ch));                 \
    short8 wf0 = *(const short8*)(b_ + 4096 + swz(g0r + l31, ch));         \
    short8 wf1 = *(const short8*)(b_ + 4096 + swz(g1r + l31, ch));         \
    a00 = mfma_bf16_32(af0, wf0, a00);                                     \
    a01 = mfma_bf16_32(af0, wf1, a01);                                     \
    a10 = mfma_bf16_32(af1, wf0, a10);                                     \
    a11 = mfma_bf16_32(af1, wf1, a11);                                     \
  }

  const int nIter = K >> 6;     // 64-k chunks; 32 (K=2048) or 8 (K=512), even
  LDSET(Aa, Aw0, Aw1, 0);
  LDSET(Ba, Bw0, Bw1, 64);
  for (int it = 0; it < nIter; it += 2) {
    STAGE(0, Aa, Aw0, Aw1);
    __syncthreads();
    { const int kn = (it + 2 < nIter) ? ((it + 2) << 6) : 0;
      LDSET(Aa, Aw0, Aw1, kn); }
    COMP(0);
    STAGE(1, Ba, Bw0, Bw1);
    __syncthreads();
    { const int kn = (it + 3 < nIter) ? ((it + 3) << 6) : 64;
      LDSET(Ba, Bw0, Bw1, kn); }
    COMP(1);
  }
#undef LDSET
#undef STAGE
#undef COMP

  // ---- cross-slice reduction: tiles (gate, mh) summed over s4 = 0..3 ----
  __syncthreads();
  if (s4 != 0) {
    float* rp = red[(s4 - 1) * 2 + gp];
#pragma unroll
    for (int r = 0; r < 16; ++r) rp[(0 * 16 + r) * 64 + lane] = a00[r];
#pragma unroll
    for (int r = 0; r < 16; ++r) rp[(1 * 16 + r) * 64 + lane] = a01[r];
#pragma unroll
    for (int r = 0; r < 16; ++r) rp[(2 * 16 + r) * 64 + lane] = a10[r];
#pragma unroll
    for (int r = 0; r < 16; ++r) rp[(3 * 16 + r) * 64 + lane] = a11[r];
  }
  __syncthreads();
  if (s4 == 0) {
#pragma unroll
    for (int ss = 0; ss < 3; ++ss) {
      const float* rp = red[ss * 2 + gp];
#pragma unroll
      for (int r = 0; r < 16; ++r) a00[r] += rp[(0 * 16 + r) * 64 + lane];
#pragma unroll
      for (int r = 0; r < 16; ++r) a01[r] += rp[(1 * 16 + r) * 64 + lane];
#pragma unroll
      for (int r = 0; r < 16; ++r) a10[r] += rp[(2 * 16 + r) * 64 + lane];
#pragma unroll
      for (int r = 0; r < 16; ++r) a11[r] += rp[(3 * 16 + r) * 64 + lane];
    }
    // gate exchange: C layout col=lane&31, row=(reg&3)+8*(reg>>2)+4*(lane>>5)
    const int gA = gp * 2, gB = gp * 2 + 1;
#pragma unroll
    for (int r = 0; r < 16; ++r) {
      const int trow = (r & 3) + 8 * (r >> 2) + 4 * lh;
      LDSf[(gA * 64 + trow     ) * 33 + l31] = a00[r];
      LDSf[(gB * 64 + trow     ) * 33 + l31] = a01[r];
      LDSf[(gA * 64 + 32 + trow) * 33 + l31] = a10[r];
      LDSf[(gB * 64 + 32 + trow) * 33 + l31] = a11[r];
    }
  }
  __syncthreads();
  {
    const int row = tid >> 3, c0 = (tid & 7) * 4;
    const int grow = m0 + row;
#pragma unroll
    for (int j = 0; j < 4; ++j) {
      const int col = c0 + j;
      const int gcol = gh0 + col;
      const float R   = sigmoidf_(LDSf[(0 * 64 + row) * 33 + col] + cr[gcol]);
      const float U   = sigmoidf_(LDSf[(1 * 64 + row) * 33 + col] + cz[gcol]);
      const float HNv = hn_scale * LDSf[(3 * 64 + row) * 33 + col] + chn[gcol];
      const float Nv  = tanhf(LDSf[(2 * 64 + row) * 33 + col] + cn[gcol] + R * HNv);
      const float ho  = h_old ? h_old[(size_t)grow * H_ + gcol] : 0.0f;
      const float hv  = (1.0f - U) * Nv + U * ho;
      h_new[(size_t)grow * H_ + gcol]  = hv;
      h_hist[(size_t)grow * H_ + gcol] = f2bf(hv);
    }
  }
}

// ---------------------------------------------------------------------------
// All 3 Wsum GEMMs: 128x128 tiles, 512 thr, 8 waves (2m x 4n), dbuf.
// C_g = w_ih_g @ lin_w^T (+ w_hh_g for g<2) -> row-major bf16.
// Grid (16, 48): mi = x, g = y>>4, nj = y&15.
// ---------------------------------------------------------------------------
__global__ __launch_bounds__(512) void gemm128_wsum(
    const unsigned short* __restrict__ w_ih_q,
    const unsigned short* __restrict__ lin_wT_q,
    const float* __restrict__ w_hh,
    unsigned short* __restrict__ Wsum_r,
    unsigned short* __restrict__ Wsum_z,
    unsigned short* __restrict__ Wn_c)
{
  __shared__ __align__(16) unsigned short sA[2][8192];   // 32 KB
  __shared__ __align__(16) unsigned short sB[2][8192];   // 32 KB
  const int g = blockIdx.y >> 4, nj = blockIdx.y & 15;
  const unsigned short* Aq = w_ih_q + (size_t)g * H_ * Z_;
  const float* adds = (g < 2) ? (w_hh + (size_t)g * H_ * H_) : nullptr;
  unsigned short* outw = (g == 0) ? Wsum_r : (g == 1) ? Wsum_z : Wn_c;
  const int K = Z_;
  const int m0 = blockIdx.x * 128, n0 = nj * 128;
  const int tid = threadIdx.x;
  const int wave = tid >> 6, lane = tid & 63;
  const int wr = wave & 1, wc = wave >> 1;
  const int lh = lane >> 5, l31 = lane & 31;
  const int srow = tid >> 2, sc0 = (tid & 3) * 2;
  const size_t aoff = (size_t)(m0 + srow) * K + sc0 * 8;
  const size_t boff = (size_t)(n0 + srow) * K + sc0 * 8;
  const int sd0 = swz(srow, sc0), sd1 = swz(srow, sc0 + 1);
  f32x16 acc0 = {}, acc1 = {};
  uint4 A0, A1, B0, B1, C0, C1, D0, D1;
#define LD(a0, a1, b0, b1, k0)                              \
  { const int kk_ = (k0);                                   \
    a0 = *(const uint4*)(Aq + aoff + kk_);                  \
    a1 = *(const uint4*)(Aq + aoff + kk_ + 8);              \
    b0 = *(const uint4*)(lin_wT_q + boff + kk_);            \
    b1 = *(const uint4*)(lin_wT_q + boff + kk_ + 8); }
#define ST(s, a0, a1, b0, b1)                               \
  { *(uint4*)(sA[s] + sd0) = a0; *(uint4*)(sA[s] + sd1) = a1; \
    *(uint4*)(sB[s] + sd0) = b0; *(uint4*)(sB[s] + sd1) = b1; }
#define CP(s)                                               \
  { _Pragma("unroll")                                       \
    for (int ks = 0; ks < 4; ++ks) {                        \
      const int ch = ks * 2 + lh;                           \
      short8 af0 = *(const short8*)(sA[s] + swz(wr * 64 + l31, ch));      \
      short8 af1 = *(const short8*)(sA[s] + swz(wr * 64 + 32 + l31, ch)); \
      short8 bf  = *(const short8*)(sB[s] + swz(wc * 32 + l31, ch));      \
      acc0 = mfma_bf16_32(af0, bf, acc0);                   \
      acc1 = mfma_bf16_32(af1, bf, acc1); } }
  const int nIter = K >> 6;   // 8
  LD(A0, A1, B0, B1, 0);
  LD(C0, C1, D0, D1, 64);
  for (int it = 0; it < nIter; it += 2) {
    ST(0, A0, A1, B0, B1);
    __syncthreads();
    { const int kn = (it + 2 < nIter) ? ((it + 2) << 6) : 0; LD(A0, A1, B0, B1, kn); }
    CP(0);
    ST(1, C0, C1, D0, D1);
    __syncthreads();
    { const int kn = (it + 3 < nIter) ? ((it + 3) << 6) : 64; LD(C0, C1, D0, D1, kn); }
    CP(1);
  }
#undef LD
#undef ST
#undef CP
#pragma unroll
  for (int i = 0; i < 2; ++i) {
    const f32x16 a = i ? acc1 : acc0;
#pragma unroll
    for (int r = 0; r < 16; ++r) {
      const int row = m0 + wr * 64 + i * 32 + (r & 3) + 8 * (r >> 2) + 4 * lh;
      const int col = n0 + wc * 32 + l31;
      float val = a[r];
      if (adds) val += adds[(size_t)row * H_ + col];
      outw[(size_t)row * H_ + col] = f2bf(val);
    }
  }
}

// ---------------------------------------------------------------------------
// Generic bf16 GEMM, C = A @ B^T (+add)(+bias)(*scale). WG tile 32x64.
// Grid = (M/32, N/64). Used only for the small x0 GEMM (M=256).
// ---------------------------------------------------------------------------
__global__ __launch_bounds__(256) void gemm_bt(
    const unsigned short* __restrict__ A,
    const unsigned short* __restrict__ Bw,
    int K,
    const float* __restrict__ addsrc, int add_ld,
    const float* __restrict__ bias,
    const float* __restrict__ scale_ptr,
    unsigned short* __restrict__ out_bf,
    float* __restrict__ out_f, int ldo)
{
  __shared__ unsigned short sA[32 * 64];
  __shared__ unsigned short sB[64 * 64];
  const int tid  = threadIdx.x;
  const int m0   = blockIdx.x * 32, n0 = blockIdx.y * 64;
  const int wave = tid >> 6, lane = tid & 63;
  const int wr = wave & 1, wc = wave >> 1;
  const int q = lane >> 4, c16 = lane & 15;
  const int lr = tid >> 3, lc8 = tid & 7;
  f32x4 acc0 = {}, acc1 = {};
  const size_t rowA  = (size_t)(m0 + lr) * K;
  const size_t rowB0 = (size_t)(n0 + lr) * K;
  const size_t rowB1 = (size_t)(n0 + 32 + lr) * K;
  for (int k0 = 0; k0 < K; k0 += 64) {
    const int gc = k0 + lc8 * 8;
    uint4 ra  = *(const uint4*)(A  + rowA  + gc);
    uint4 rb0 = *(const uint4*)(Bw + rowB0 + gc);
    uint4 rb1 = *(const uint4*)(Bw + rowB1 + gc);
    __syncthreads();
    *(uint4*)(sA + swz(lr, lc8))      = ra;
    *(uint4*)(sB + swz(lr, lc8))      = rb0;
    *(uint4*)(sB + swz(32 + lr, lc8)) = rb1;
    __syncthreads();
#pragma unroll
    for (int kk = 0; kk < 2; ++kk) {
      const int arow = wr * 16 + c16;
      short8 af = *(const short8*)(sA + swz(arow, kk * 4 + q));
      const int brow = wc * 32 + c16;
      short8 b0 = *(const short8*)(sB + swz(brow, kk * 4 + q));
      acc0 = mfma_bf16(af, b0, acc0);
      short8 b1 = *(const short8*)(sB + swz(brow + 16, kk * 4 + q));
      acc1 = mfma_bf16(af, b1, acc1);
    }
  }
  const float scale = scale_ptr ? *scale_ptr : 1.0f;
#pragma unroll
  for (int cf = 0; cf < 2; ++cf) {
    f32x4 a = cf ? acc1 : acc0;
#pragma unroll
    for (int v = 0; v < 4; ++v) {
      const int row = m0 + wr * 16 + q * 4 + v;
      const int col = n0 + wc * 32 + cf * 16 + c16;
      float val = a[v] * scale;
      if (addsrc) val += addsrc[(size_t)row * add_ld + col];
      if (bias)   val += bias[col];
      if (out_f)  out_f[(size_t)row * ldo + col] = val;
      if (out_bf) out_bf[(size_t)row * ldo + col] = f2bf(val);
    }
  }
}

// ---------------------------------------------------------------------------
// 64x64-tile bf16 GEMM, C = A @ B^T (+add)(+bias). Grid = (M/64, N/64).
// 4 waves of 32x32. Reg-prefetch pipeline. (outs GEMM)
// ---------------------------------------------------------------------------
__global__ __launch_bounds__(256) void gemm_bt64(
    const unsigned short* __restrict__ A,
    const unsigned short* __restrict__ Bw,
    int K,
    const float* __restrict__ addsrc, int add_ld,
    const float* __restrict__ bias,
    unsigned short* __restrict__ out_bf,
    float* __restrict__ out_f, int ldo)
{
  __shared__ unsigned short sA[64 * 64];
  __shared__ unsigned short sB[64 * 64];
  const int tid  = threadIdx.x;
  const int m0   = blockIdx.x * 64, n0 = blockIdx.y * 64;
  const int wave = tid >> 6, lane = tid & 63;
  const int wr = wave & 1, wc = wave >> 1;
  const int q = lane >> 4, c16 = lane & 15;
  const int lr = tid >> 3, lc8 = tid & 7;
  f32x4 acc[2][2] = {};
  const size_t aoff = (size_t)(m0 + lr) * K;
  const size_t boff = (size_t)(n0 + lr) * K;
  const size_t s32  = (size_t)32 * K;

  uint4 ra0, ra1, rb0, rb1;
  auto LOAD = [&](int k0) {
    const int gc = k0 + lc8 * 8;
    ra0 = *(const uint4*)(A  + aoff + gc);
    ra1 = *(const uint4*)(A  + aoff + s32 + gc);
    rb0 = *(const uint4*)(Bw + boff + gc);
    rb1 = *(const uint4*)(Bw + boff + s32 + gc);
  };

  const int nIter = K >> 6;
  LOAD(0);
  for (int it = 0; it < nIter; ++it) {
    __syncthreads();
    *(uint4*)(sA + swz(lr, lc8))      = ra0;
    *(uint4*)(sA + swz(lr + 32, lc8)) = ra1;
    *(uint4*)(sB + swz(lr, lc8))      = rb0;
    *(uint4*)(sB + swz(lr + 32, lc8)) = rb1;
    __syncthreads();
    if (it + 1 < nIter) LOAD((it + 1) << 6);
#pragma unroll
    for (int kk = 0; kk < 2; ++kk) {
      short8 af0 = *(const short8*)(sA + swz(wr * 32 + c16,      kk * 4 + q));
      short8 af1 = *(const short8*)(sA + swz(wr * 32 + 16 + c16, kk * 4 + q));
      short8 bf0 = *(const short8*)(sB + swz(wc * 32 + c16,      kk * 4 + q));
      short8 bf1 = *(const short8*)(sB + swz(wc * 32 + 16 + c16, kk * 4 + q));
      acc[0][0] = mfma_bf16(af0, bf0, acc[0][0]);
      acc[0][1] = mfma_bf16(af0, bf1, acc[0][1]);
      acc[1][0] = mfma_bf16(af1, bf0, acc[1][0]);
      acc[1][1] = mfma_bf16(af1, bf1, acc[1][1]);
    }
  }
#pragma unroll
  for (int i = 0; i < 2; ++i) {
#pragma unroll
    for (int j = 0; j < 2; ++j) {
#pragma unroll
      for (int v = 0; v < 4; ++v) {
        const int row = m0 + wr * 32 + i * 16 + q * 4 + v;
        const int col = n0 + wc * 32 + j * 16 + c16;
        float val = acc[i][j][v];
        if (addsrc) val += addsrc[(size_t)row * add_ld + col];
        if (bias)   val += bias[col];
        if (out_f)  out_f[(size_t)row * ldo + col] = val;
        if (out_bf) out_bf[(size_t)row * ldo + col] = f2bf(val);
      }
    }
  }
}

// ---------------------------------------------------------------------------
// merged quantization of all bf16 operands (one launch)
// ---------------------------------------------------------------------------
__global__ __launch_bounds__(256) void quant_all(
    const float* __restrict__ z, const float* __restrict__ fc_w,
    const float* __restrict__ w_ih, const float* __restrict__ w_hh,
    const float* __restrict__ lin_w,
    unsigned short* __restrict__ z_q, unsigned short* __restrict__ fc_w_q,
    unsigned short* __restrict__ w_ih_q, unsigned short* __restrict__ w_hhn_q,
    unsigned short* __restrict__ lin_w_q)
{
  const int i = blockIdx.x * 256 + threadIdx.x;
  if (i >= 2195456) return;
  const float4* src; ushort4* dst; int idx;
  if (i < 32768)        { src = (const float4*)z;     dst = (ushort4*)z_q;     idx = i; }
  else if (i < 98304)   { src = (const float4*)fc_w;  dst = (ushort4*)fc_w_q;  idx = i - 32768; }
  else if (i < 884736)  { src = (const float4*)w_ih;  dst = (ushort4*)w_ih_q;  idx = i - 98304; }
  else if (i < 1933312) { src = (const float4*)(w_hh + (size_t)2 * H_ * H_);
                          dst = (ushort4*)w_hhn_q;    idx = i - 884736; }
  else                  { src = (const float4*)lin_w; dst = (ushort4*)lin_w_q; idx = i - 1933312; }
  float4 v = src[idx];
  ushort4 o; o.x = f2bf(v.x); o.y = f2bf(v.y); o.z = f2bf(v.z); o.w = f2bf(v.w);
  dst[idx] = o;
}

// lin_w [512][2048] f32 -> lin_wT [2048][512] bf16
__global__ __launch_bounds__(256) void transq(const float* __restrict__ s,
                                              unsigned short* __restrict__ d) {
  __shared__ float tile[32][33];
  const int tx = threadIdx.x & 31, ty = threadIdx.x >> 5;
  const int k0 = blockIdx.x * 32, z0 = blockIdx.y * 32;
#pragma unroll
  for (int j = 0; j < 4; ++j)
    tile[ty + j * 8][tx] = s[(size_t)(z0 + ty + j * 8) * H_ + k0 + tx];
  __syncthreads();
#pragma unroll
  for (int j = 0; j < 4; ++j)
    d[(size_t)(k0 + ty + j * 8) * Z_ + z0 + tx] = f2bf(tile[tx][ty + j * 8]);
}

// t1 = W^T u.  grid 8, block 256 (4 waves x 128 rows each).
__global__ void sigma1(const float* __restrict__ W, const float* __restrict__ u,
                       float* __restrict__ t1) {
  __shared__ float part[4][64];
  const int lane = threadIdx.x & 63, wv = threadIdx.x >> 6;
  const int col = blockIdx.x * 64 + lane;
  float s = 0.f;
  for (int r = wv * 128; r < wv * 128 + 128; ++r)
    s += W[(size_t)r * Z_ + col] * u[r];
  part[wv][lane] = s;
  __syncthreads();
  if (wv == 0)
    t1[col] = part[0][lane] + part[1][lane] + part[2][lane] + part[3][lane];
}

// t2 = W @ normalize(t1); per-WG redundant norm recompute (t1 is 2KB, L2-hot).
__global__ void sigma2(const float* __restrict__ W, const float* __restrict__ t1,
                       float* __restrict__ t2) {
  __shared__ float red[256];
  const int tid = threadIdx.x;
  float p = 0.f;
  for (int c = tid; c < Z_; c += 256) { float v = t1[c]; p += v * v; }
  red[tid] = p;
  __syncthreads();
  for (int s = 128; s > 0; s >>= 1) {
    if (tid < s) red[tid] += red[tid + s];
    __syncthreads();
  }
  const float invn = 1.0f / (sqrtf(red[0]) + 1e-12f);
  const int lane = tid & 63, wv = tid >> 6;
  const int row = blockIdx.x * 4 + wv;
  float s = 0.f;
  for (int c = lane; c < Z_; c += 64) s += W[(size_t)row * Z_ + c] * t1[c];
#pragma unroll
  for (int off = 32; off > 0; off >>= 1) s += __shfl_down(s, off);
  if (lane == 0) t2[row] = s * invn;
}

__global__ void sigma3(const float* __restrict__ t2, float* __restrict__ inv_sig) {
  __shared__ float red[256];
  int t = threadIdx.x;
  float v0 = t2[t], v1 = t2[t + 256];
  red[t] = v0 * v0 + v1 * v1;
  __syncthreads();
  for (int s = 128; s > 0; s >>= 1) {
    if (t < s) red[t] += red[t + s];
    __syncthreads();
  }
  if (t == 0) {
    float s2  = red[0];
    float sig = s2 / (sqrtf(s2) + 1e-12f);
    inv_sig[0] = 1.0f / sig;
  }
}

// dvec[row] = dot(w_ih[row], lin_b) fused with the gate-constant writes.
__global__ __launch_bounds__(256) void dots2_k(
    const float* __restrict__ w, const float* __restrict__ lb,
    const float* __restrict__ b_ih, const float* __restrict__ b_hh,
    float* __restrict__ c0r, float* __restrict__ c0z, float* __restrict__ c0n,
    float* __restrict__ c1r, float* __restrict__ c1z, float* __restrict__ c1n,
    float* __restrict__ chn)
{
  const int wave = threadIdx.x >> 6, lane = threadIdx.x & 63;
#pragma unroll
  for (int i = 0; i < 4; ++i) {
    int row = blockIdx.x * 16 + wave * 4 + i;
    float s = 0.f;
    for (int c = lane; c < Z_; c += 64) s += w[(size_t)row * Z_ + c] * lb[c];
#pragma unroll
    for (int off = 32; off > 0; off >>= 1) s += __shfl_down(s, off);
    if (lane == 0) {
      const int g = row >> 11, j = row & 2047;
      const float bi = b_ih[row], bh = b_hh[row];
      if (g == 0)      { c0r[j] = bi + bh; c1r[j] = bi + bh + s; }
      else if (g == 1) { c0z[j] = bi + bh; c1z[j] = bi + bh + s; }
      else             { c0n[j] = bi;      c1n[j] = bi + s;      chn[j] = bh; }
    }
  }
}

// BN over batch per (t,z) + transpose [T,B,Z] -> [B,T,Z]. Grid (16, 8).
__global__ __launch_bounds__(256) void bn_k(const float* __restrict__ outs,
                                            float* __restrict__ y) {
  __shared__ float s_sum[4][64], s_sq[4][64], s_mean[64], s_inv[64];
  const int t = blockIdx.x, zb = blockIdx.y;
  const int zl = threadIdx.x & 63, bp = threadIdx.x >> 6;
  const int z = zb * 64 + zl;
  float sum = 0.f, sq = 0.f;
  for (int b = bp * 64; b < bp * 64 + 64; ++b) {
    float v = outs[(size_t)(t * 256 + b) * Z_ + z];
    sum += v; sq += v * v;
  }
  s_sum[bp][zl] = sum; s_sq[bp][zl] = sq;
  __syncthreads();
  if (bp == 0) {
    float S = s_sum[0][zl] + s_sum[1][zl] + s_sum[2][zl] + s_sum[3][zl];
    float Q = s_sq[0][zl] + s_sq[1][zl] + s_sq[2][zl] + s_sq[3][zl];
    float mean = S * (1.0f / 256.0f);
    float var  = Q * (1.0f / 256.0f) - mean * mean;
    s_mean[zl] = mean;
    s_inv[zl]  = rsqrtf(var + 1e-5f);
  }
  __syncthreads();
  const float mean = s_mean[zl], inv = s_inv[zl];
  for (int b = bp * 64; b < bp * 64 + 64; ++b) {
    float v = outs[(size_t)(t * 256 + b) * Z_ + z];
    y[(size_t)(b * T_ + t) * Z_ + z] = (v - mean) * inv;
  }
}

// ---------------------------------------------------------------------------
extern "C" void kernel_launch(void* const* d_in, const int* in_sizes, int n_in,
                              void* d_out, int out_size, void* d_ws, size_t ws_size,
                              hipStream_t stream) {
  const float* z     = (const float*)d_in[0];
  const float* fc_w  = (const float*)d_in[1];
  const float* fc_b  = (const float*)d_in[2];
  const float* fc_u  = (const float*)d_in[3];
  const float* w_ih  = (const float*)d_in[4];
  const float* w_hh  = (const float*)d_in[5];
  const float* b_ih  = (const float*)d_in[6];
  const float* b_hh  = (const float*)d_in[7];
  const float* lin_w = (const float*)d_in[8];
  const float* lin_b = (const float*)d_in[9];
  float* out = (float*)d_out;

  char* ws = (char*)d_ws;
  size_t off = 0;
  auto alloc = [&](size_t bytes) -> void* {
    off = (off + 255) & ~(size_t)255;
    void* p = ws + off;
    off += bytes;
    return p;
  };
  unsigned short* w_ih_q   = (unsigned short*)alloc((size_t)H3_ * Z_ * 2);
  unsigned short* w_hhn_q  = (unsigned short*)alloc((size_t)H_ * H_ * 2);
  unsigned short* lin_w_q  = (unsigned short*)alloc((size_t)Z_ * H_ * 2);
  unsigned short* lin_wT_q = (unsigned short*)alloc((size_t)Z_ * H_ * 2);
  unsigned short* fc_w_q   = (unsigned short*)alloc((size_t)Z_ * Z_ * 2);
  unsigned short* z_q      = (unsigned short*)alloc((size_t)B_ * Z_ * 2);
  unsigned short* x0_q     = (unsigned short*)alloc((size_t)B_ * Z_ * 2);
  unsigned short* Wsum_r   = (unsigned short*)alloc((size_t)H_ * H_ * 2);
  unsigned short* Wsum_z   = (unsigned short*)alloc((size_t)H_ * H_ * 2);
  unsigned short* Wn_c     = (unsigned short*)alloc((size_t)H_ * H_ * 2);
  unsigned short* Hhist    = (unsigned short*)alloc((size_t)T_ * B_ * H_ * 2);
  float* h_f32 = (float*)alloc((size_t)2 * B_ * H_ * 4);
  float* outs  = (float*)alloc((size_t)T_ * B_ * Z_ * 4);
  float* c0r = (float*)alloc(H_ * 4);
  float* c0z = (float*)alloc(H_ * 4);
  float* c0n = (float*)alloc(H_ * 4);
  float* c1r = (float*)alloc(H_ * 4);
  float* c1z = (float*)alloc(H_ * 4);
  float* c1n = (float*)alloc(H_ * 4);
  float* chn = (float*)alloc(H_ * 4);
  float* t1v = (float*)alloc(Z_ * 4);
  float* t2v = (float*)alloc(Z_ * 4);
  float* invsig = (float*)alloc(256);
  (void)in_sizes; (void)n_in; (void)out_size; (void)ws_size;

  quant_all<<<dim3((2195456 + 255) / 256), 256, 0, stream>>>(
      z, fc_w, w_ih, w_hh, lin_w, z_q, fc_w_q, w_ih_q, w_hhn_q, lin_w_q);
  transq<<<dim3(64, 16), 256, 0, stream>>>(lin_w, lin_wT_q);
  sigma1<<<8, 256, 0, stream>>>(fc_w, fc_u, t1v);
  sigma2<<<128, 256, 0, stream>>>(fc_w, t1v, t2v);
  sigma3<<<1, 256, 0, stream>>>(t2v, invsig);
  dots2_k<<<384, 256, 0, stream>>>(w_ih, lin_b, b_ih, b_hh,
                                   c0r, c0z, c0n, c1r, c1z, c1n, chn);

  // x0 = (z @ fc_w^T) * inv_sigma + fc_b   -> bf16
  gemm_bt<<<dim3(B_ / 32, Z_ / 64), 256, 0, stream>>>(
      z_q, fc_w_q, Z_, nullptr, 0, fc_b, invsig, x0_q, nullptr, Z_);

  // W_comb_g = w_ih_g @ lin_w (+ w_hh_g for r,z) -> bf16 [2048][2048], 1 launch
  gemm128_wsum<<<dim3(H_ / 128, 48), 512, 0, stream>>>(
      w_ih_q, lin_wT_q, w_hh, Wsum_r, Wsum_z, Wn_c);

  for (int t = 0; t < T_; ++t) {
    if (t == 0) {
      gru_step7<<<256, 512, 0, stream>>>(
          x0_q, Z_,
          w_ih_q, w_ih_q + (size_t)H_ * Z_, w_ih_q + (size_t)2 * H_ * Z_,
          w_ih_q /* dummy, scaled by 0 */,
          c0r, c0z, c0n, chn, 0.0f, nullptr, h_f32, Hhist);
    } else {
      gru_step7<<<256, 512, 0, stream>>>(
          Hhist + (size_t)(t - 1) * B_ * H_, H_,
          Wsum_r, Wsum_z, Wn_c, w_hhn_q,
          c1r, c1z, c1n, chn, 1.0f,
          h_f32 + (size_t)((t - 1) & 1) * B_ * H_,
          h_f32 + (size_t)(t & 1) * B_ * H_,
          Hhist + (size_t)t * B_ * H_);
    }
  }

  // outs[t*256+b][z] = Hhist[t][b] @ lin_w^T + lin_b   (f32)
  gemm_bt64<<<dim3(T_ * B_ / 64, Z_ / 64), 256, 0, stream>>>(
      Hhist, lin_w_q, H_, nullptr, 0, lin_b, nullptr, outs, Z_);

  bn_k<<<dim3(T_, Z_ / 64), 256, 0, stream>>>(outs, out);
}